// Round 1
// baseline (193.929 us; speedup 1.0000x reference)
//
#include <hip/hip_runtime.h>

#define N_NODES 100000
#define N_EDGES 600000
#define D 128
#define NC 24        // 3 feature columns * 8 vocab
#define TM 64        // nodes per block
#define LDW 132      // padded leading dim for W tile in LDS
#define LDH 132      // padded leading dim for hS tile in LDS

// ---------------------------------------------------------------------------
// Kernel 1: per-node histogram of (feature, value) pairs.
// agg[n] = h[n] * sum_{f,v} count[n][f][v] * bond_emb[f][v]
// ---------------------------------------------------------------------------
__global__ __launch_bounds__(256) void hist_kernel(const int* __restrict__ ef,
                                                   const int* __restrict__ dst,
                                                   int* __restrict__ counts) {
    int e = blockIdx.x * 256 + threadIdx.x;
    if (e >= N_EDGES) return;
    int n  = dst[e];
    int f0 = ef[e * 3 + 0];
    int f1 = ef[e * 3 + 1];
    int f2 = ef[e * 3 + 2];
    int* base = counts + n * NC;
    atomicAdd(base + f0, 1);
    atomicAdd(base + 8 + f1, 1);
    atomicAdd(base + 16 + f2, 1);
}

// ---------------------------------------------------------------------------
// Kernel 2 (fused): S[n] = sum_j cnt[n][j]*emb[j];  hS = h[n]*S[n];
//                   out[n] = hS @ W^T + b   (f32 register-tiled GEMM)
// Block: 512 threads, TM=64 nodes, full 128 output cols.
// LDS: W 128x132 (66KB) + hS 64x132 (33KB) + emb 24x128 (12KB) + cnt (6KB)
// ---------------------------------------------------------------------------
__global__ __launch_bounds__(512) void fused_kernel(const float* __restrict__ h,
                                                    const int*   __restrict__ counts,
                                                    const float* __restrict__ emb,
                                                    const float* __restrict__ W,
                                                    const float* __restrict__ b,
                                                    float* __restrict__ out) {
    __shared__ float sW[128 * LDW];
    __shared__ float sHS[TM * LDH];
    __shared__ float sEmb[NC * 128];
    __shared__ float sCntF[TM * NC];

    const int tid = threadIdx.x;
    const int n0  = blockIdx.x * TM;

    // --- stage W into LDS (padded rows), vectorized float4 ---
    #pragma unroll
    for (int i = 0; i < 8; ++i) {
        int q   = tid + 512 * i;          // quad index, 4096 total
        int row = q >> 5;                 // 32 quads per 128-float row
        int qc  = q & 31;
        float4 v = reinterpret_cast<const float4*>(W)[q];
        *reinterpret_cast<float4*>(&sW[row * LDW + (qc << 2)]) = v;
    }
    // --- stage bond embeddings (24x128) ---
    for (int q = tid; q < NC * D / 4; q += 512) {
        reinterpret_cast<float4*>(sEmb)[q] =
            reinterpret_cast<const float4*>(emb)[q];
    }
    // --- stage this tile's counts as floats ---
    for (int i = tid; i < TM * NC; i += 512) {
        int n = n0 + i / NC;
        sCntF[i] = (n < N_NODES) ? (float)counts[n * NC + (i % NC)] : 0.0f;
    }
    __syncthreads();

    // --- compute hS tile: 64 nodes x 128 dims, 16 elems/thread ---
    #pragma unroll
    for (int i = 0; i < TM * D / 512; ++i) {   // 16 iterations
        int idx = tid + 512 * i;
        int nl  = idx >> 7;
        int d   = idx & 127;
        int n   = n0 + nl;
        const float* c = &sCntF[nl * NC];
        float s = 0.0f;
        #pragma unroll
        for (int j = 0; j < NC; ++j)
            s += c[j] * sEmb[j * D + d];
        float hv = (n < N_NODES) ? h[n * D + d] : 0.0f;
        sHS[nl * LDH + d] = hv * s;
    }
    __syncthreads();

    // --- GEMM: thread (ty,tx) computes 4 nodes x 4 cols ---
    const int ty = tid >> 5;      // 0..15 -> node group
    const int tx = tid & 31;      // 0..31 -> col base
    const int nb = ty << 2;

    float acc[4][4];
    #pragma unroll
    for (int i = 0; i < 4; ++i) {
        float bv = b[tx + (i << 5)];
        #pragma unroll
        for (int m = 0; m < 4; ++m) acc[m][i] = bv;
    }

    #pragma unroll 4
    for (int k4 = 0; k4 < 32; ++k4) {
        float4 av[4], wv[4];
        #pragma unroll
        for (int m = 0; m < 4; ++m)
            av[m] = *reinterpret_cast<const float4*>(&sHS[(nb + m) * LDH + (k4 << 2)]);
        #pragma unroll
        for (int i = 0; i < 4; ++i)
            wv[i] = *reinterpret_cast<const float4*>(&sW[(tx + (i << 5)) * LDW + (k4 << 2)]);
        #pragma unroll
        for (int m = 0; m < 4; ++m)
            #pragma unroll
            for (int i = 0; i < 4; ++i)
                acc[m][i] += av[m].x * wv[i].x + av[m].y * wv[i].y +
                             av[m].z * wv[i].z + av[m].w * wv[i].w;
    }

    // --- write out ---
    #pragma unroll
    for (int m = 0; m < 4; ++m) {
        int n = n0 + nb + m;
        if (n < N_NODES) {
            #pragma unroll
            for (int i = 0; i < 4; ++i)
                out[n * D + tx + (i << 5)] = acc[m][i];
        }
    }
}

extern "C" void kernel_launch(void* const* d_in, const int* in_sizes, int n_in,
                              void* d_out, int out_size, void* d_ws, size_t ws_size,
                              hipStream_t stream) {
    const float* h    = (const float*)d_in[0];
    const int*   ef   = (const int*)d_in[1];
    const int*   dst  = (const int*)d_in[2];
    const float* emb  = (const float*)d_in[3];
    const float* W    = (const float*)d_in[4];
    const float* b    = (const float*)d_in[5];
    float*       out  = (float*)d_out;
    int*         counts = (int*)d_ws;

    hipMemsetAsync(counts, 0, N_NODES * NC * sizeof(int), stream);
    hist_kernel<<<(N_EDGES + 255) / 256, 256, 0, stream>>>(ef, dst, counts);
    fused_kernel<<<(N_NODES + TM - 1) / TM, 512, 0, stream>>>(h, counts, emb, W, b, out);
}

// Round 2
// 133.505 us; speedup vs baseline: 1.4526x; 1.4526x over previous
//
#include <hip/hip_runtime.h>

#define NN 100000
#define NE 600000
#define D 128
#define NCNT 24
#define TM 64          // nodes per block tile
#define LDA 136        // bf16 elems per padded LDS row (272 B)

typedef __attribute__((ext_vector_type(8))) short bf16x8;
typedef __attribute__((ext_vector_type(4))) float f32x4;

__device__ __forceinline__ unsigned short f2bf(float x) {
    unsigned u = __float_as_uint(x);
    u += 0x7FFFu + ((u >> 16) & 1u);   // RNE
    return (unsigned short)(u >> 16);
}
__device__ __forceinline__ float bf2f(unsigned short s) {
    return __uint_as_float(((unsigned)s) << 16);
}
__device__ __forceinline__ unsigned pack2(unsigned short a, unsigned short b) {
    return (unsigned)a | ((unsigned)b << 16);
}

// ---------------------------------------------------------------------------
// prep: zero counts (2.4M ints) + split W into bf16 hi/lo (wsplit[2][128*128])
// ---------------------------------------------------------------------------
__global__ __launch_bounds__(256) void prep_kernel(const float* __restrict__ W,
                                                   int* __restrict__ counts,
                                                   unsigned short* __restrict__ wsplit) {
    int bid = blockIdx.x;
    if (bid < 2344) {
        int c = bid * 256 + threadIdx.x;           // int4 index
        if (c < 600000) reinterpret_cast<int4*>(counts)[c] = make_int4(0, 0, 0, 0);
    } else {
        int idx = (bid - 2344) * 256 + threadIdx.x; // 0..16383
        float w = W[idx];
        unsigned short hi = f2bf(w);
        unsigned short lo = f2bf(w - bf2f(hi));
        wsplit[idx] = hi;
        wsplit[16384 + idx] = lo;
    }
}

// ---------------------------------------------------------------------------
// hist: 4 edges per thread, int4 loads, 3 atomics per edge
// ---------------------------------------------------------------------------
__global__ __launch_bounds__(256) void hist_kernel(const int* __restrict__ ef,
                                                   const int* __restrict__ dst,
                                                   int* __restrict__ counts) {
    int g = blockIdx.x * 256 + threadIdx.x;        // 4-edge group
    if (g >= NE / 4) return;
    int4 d4 = reinterpret_cast<const int4*>(dst)[g];
    int4 f0 = reinterpret_cast<const int4*>(ef)[g * 3 + 0];
    int4 f1 = reinterpret_cast<const int4*>(ef)[g * 3 + 1];
    int4 f2 = reinterpret_cast<const int4*>(ef)[g * 3 + 2];
    int f[12] = {f0.x, f0.y, f0.z, f0.w, f1.x, f1.y, f1.z, f1.w, f2.x, f2.y, f2.z, f2.w};
    int dd[4] = {d4.x, d4.y, d4.z, d4.w};
    #pragma unroll
    for (int i = 0; i < 4; ++i) {
        int* base = counts + dd[i] * NCNT;
        atomicAdd(base + f[i * 3 + 0], 1);
        atomicAdd(base + 8 + f[i * 3 + 1], 1);
        atomicAdd(base + 16 + f[i * 3 + 2], 1);
    }
}

// ---------------------------------------------------------------------------
// fused: S = cnt@emb (f32, LDS-broadcast), hS = h*S, split bf16 hi/lo,
//        out = hS @ W^T + b via 3-pass bf16 MFMA (hi*hi + lo*hi + hi*lo)
// 512 threads = 8 waves; tile 64 nodes x 128 cols; 1 block/CU (123 KB LDS)
// ---------------------------------------------------------------------------
__global__ __launch_bounds__(512, 2) void fused_kernel(
        const float* __restrict__ h,
        const int* __restrict__ counts,
        const float* __restrict__ emb,
        const unsigned short* __restrict__ wsplit,
        const float* __restrict__ b,
        float* __restrict__ out) {
    __shared__ unsigned short sA[2][TM * LDA];     // 34816 B  hS hi/lo
    __shared__ unsigned short sW[2][128 * LDA];    // 69632 B  W  hi/lo
    __shared__ float sEmb[NCNT * D];               // 12288 B
    __shared__ float sCnt[TM * 25];                // 6400 B (pad 25)

    const int tid  = threadIdx.x;
    const int lane = tid & 63;
    const int w    = tid >> 6;
    const int n0   = blockIdx.x * TM;

    // --- stage W hi/lo: 4096 16B chunks, 8 per thread ---
    #pragma unroll
    for (int i = 0; i < 8; ++i) {
        int c = tid + i * 512;                     // 0..4095
        int which = c >> 11;
        int r  = (c >> 4) & 127;
        int kc = c & 15;
        uint4 v = reinterpret_cast<const uint4*>(wsplit)[c];
        *reinterpret_cast<uint4*>(&sW[which][r * LDA + kc * 8]) = v;
    }
    // --- stage emb (24x128 f32) ---
    #pragma unroll
    for (int i = 0; i < 2; ++i) {
        int c = tid + i * 512;
        if (c < 768)
            reinterpret_cast<float4*>(sEmb)[c] = reinterpret_cast<const float4*>(emb)[c];
    }
    // --- stage counts as f32 (padded 25) ---
    #pragma unroll
    for (int i = 0; i < 3; ++i) {
        int c = tid + i * 512;
        if (c < TM * NCNT) {
            int nl = c / NCNT, j = c - nl * NCNT;
            int n = n0 + nl;
            sCnt[nl * 25 + j] = (n < NN) ? (float)counts[n * NCNT + j] : 0.0f;
        }
    }
    __syncthreads();

    // --- Phase 1: lane = node, wave owns d-range [w*16, w*16+16) ---
    {
        const int node = n0 + lane;
        const bool valid = node < NN;
        float c[NCNT];
        #pragma unroll
        for (int j = 0; j < NCNT; ++j) c[j] = sCnt[lane * 25 + j];

        #pragma unroll
        for (int ch = 0; ch < 2; ++ch) {
            const int d0 = w * 16 + ch * 8;
            float s[8] = {0, 0, 0, 0, 0, 0, 0, 0};
            #pragma unroll
            for (int j = 0; j < NCNT; ++j) {       // wave-uniform -> LDS broadcast
                float4 e0 = *reinterpret_cast<const float4*>(&sEmb[j * D + d0]);
                float4 e1 = *reinterpret_cast<const float4*>(&sEmb[j * D + d0 + 4]);
                s[0] += c[j] * e0.x;  s[1] += c[j] * e0.y;
                s[2] += c[j] * e0.z;  s[3] += c[j] * e0.w;
                s[4] += c[j] * e1.x;  s[5] += c[j] * e1.y;
                s[6] += c[j] * e1.z;  s[7] += c[j] * e1.w;
            }
            float hv[8] = {0, 0, 0, 0, 0, 0, 0, 0};
            if (valid) {
                float4 h0 = *reinterpret_cast<const float4*>(&h[node * D + d0]);
                float4 h1 = *reinterpret_cast<const float4*>(&h[node * D + d0 + 4]);
                hv[0] = h0.x; hv[1] = h0.y; hv[2] = h0.z; hv[3] = h0.w;
                hv[4] = h1.x; hv[5] = h1.y; hv[6] = h1.z; hv[7] = h1.w;
            }
            unsigned short hi8[8], lo8[8];
            #pragma unroll
            for (int k = 0; k < 8; ++k) {
                float hs = hv[k] * s[k];
                hi8[k] = f2bf(hs);
                lo8[k] = f2bf(hs - bf2f(hi8[k]));
            }
            uint4 ph, pl;
            ph.x = pack2(hi8[0], hi8[1]); ph.y = pack2(hi8[2], hi8[3]);
            ph.z = pack2(hi8[4], hi8[5]); ph.w = pack2(hi8[6], hi8[7]);
            pl.x = pack2(lo8[0], lo8[1]); pl.y = pack2(lo8[2], lo8[3]);
            pl.z = pack2(lo8[4], lo8[5]); pl.w = pack2(lo8[6], lo8[7]);
            *reinterpret_cast<uint4*>(&sA[0][lane * LDA + d0]) = ph;
            *reinterpret_cast<uint4*>(&sA[1][lane * LDA + d0]) = pl;
        }
    }
    __syncthreads();

    // --- Phase 2: MFMA GEMM. wave w: mt = w>>1 (16-node group), jc = w&1 (64-col) ---
    const int mt = w >> 1;
    const int jc = w & 1;
    const int lr = lane & 15;
    const int lg = lane >> 4;

    f32x4 acc[4];
    #pragma unroll
    for (int jb = 0; jb < 4; ++jb) {
        float bv = b[jc * 64 + jb * 16 + lr];
        f32x4 t = {bv, bv, bv, bv};
        acc[jb] = t;
    }

    const int arow = mt * 16 + lr;
    const int koff = lg * 8;
    #pragma unroll
    for (int kk = 0; kk < 4; ++kk) {
        const int ke = kk * 32 + koff;             // bf16 elem offset in row
        bf16x8 ahi = *reinterpret_cast<const bf16x8*>(&sA[0][arow * LDA + ke]);
        bf16x8 alo = *reinterpret_cast<const bf16x8*>(&sA[1][arow * LDA + ke]);
        bf16x8 whi[4], wlo[4];
        #pragma unroll
        for (int jb = 0; jb < 4; ++jb) {
            int brow = jc * 64 + jb * 16 + lr;
            whi[jb] = *reinterpret_cast<const bf16x8*>(&sW[0][brow * LDA + ke]);
            wlo[jb] = *reinterpret_cast<const bf16x8*>(&sW[1][brow * LDA + ke]);
        }
        #pragma unroll
        for (int jb = 0; jb < 4; ++jb) {
            acc[jb] = __builtin_amdgcn_mfma_f32_16x16x32_bf16(ahi, whi[jb], acc[jb], 0, 0, 0);
            acc[jb] = __builtin_amdgcn_mfma_f32_16x16x32_bf16(alo, whi[jb], acc[jb], 0, 0, 0);
            acc[jb] = __builtin_amdgcn_mfma_f32_16x16x32_bf16(ahi, wlo[jb], acc[jb], 0, 0, 0);
        }
    }

    // --- store: C row = lg*4+r (node), col = lr ---
    #pragma unroll
    for (int jb = 0; jb < 4; ++jb) {
        int col = jc * 64 + jb * 16 + lr;
        #pragma unroll
        for (int r = 0; r < 4; ++r) {
            int node = n0 + mt * 16 + lg * 4 + r;
            if (node < NN) out[node * D + col] = acc[jb][r];
        }
    }
}

extern "C" void kernel_launch(void* const* d_in, const int* in_sizes, int n_in,
                              void* d_out, int out_size, void* d_ws, size_t ws_size,
                              hipStream_t stream) {
    const float* h   = (const float*)d_in[0];
    const int*   ef  = (const int*)d_in[1];
    const int*   dst = (const int*)d_in[2];
    const float* emb = (const float*)d_in[3];
    const float* W   = (const float*)d_in[4];
    const float* b   = (const float*)d_in[5];
    float*       out = (float*)d_out;

    int*            counts = (int*)d_ws;                               // 9.6 MB
    unsigned short* wsplit = (unsigned short*)((char*)d_ws + 9600000); // 64 KB

    prep_kernel<<<2344 + 64, 256, 0, stream>>>(W, counts, wsplit);
    hist_kernel<<<(NE / 4 + 255) / 256, 256, 0, stream>>>(ef, dst, counts);
    fused_kernel<<<(NN + TM - 1) / TM, 512, 0, stream>>>(h, counts, emb, wsplit, b, out);
}

// Round 3
// 93.063 us; speedup vs baseline: 2.0839x; 1.4346x over previous
//
#include <hip/hip_runtime.h>

#define NN 100000
#define NE 600000
#define D 128
#define TM 64          // nodes per fused block
#define LDA 136        // bf16 elems per padded LDS row (272 B)
#define LDE 132        // padded f32 row for sEmb
#define CW 16          // packed count words per node (125 x 4-bit)

typedef __attribute__((ext_vector_type(8))) short bf16x8;
typedef __attribute__((ext_vector_type(4))) float f32x4;

__device__ __forceinline__ unsigned short f2bf(float x) {
    unsigned u = __float_as_uint(x);
    u += 0x7FFFu + ((u >> 16) & 1u);   // RNE
    return (unsigned short)(u >> 16);
}
__device__ __forceinline__ float bf2f(unsigned short s) {
    return __uint_as_float(((unsigned)s) << 16);
}
__device__ __forceinline__ unsigned pack2(unsigned short a, unsigned short b) {
    return (unsigned)a | ((unsigned)b << 16);
}

// ---------------------------------------------------------------------------
// hist: ONE packed atomic per edge (combo = f0*25+f1*5+f2, 4-bit counters),
//       plus W hi/lo bf16 split in trailing blocks.
// ---------------------------------------------------------------------------
__global__ __launch_bounds__(256) void hist_kernel(const int* __restrict__ ef,
                                                   const int* __restrict__ dst,
                                                   unsigned* __restrict__ counts,
                                                   const float* __restrict__ W,
                                                   unsigned short* __restrict__ wsplit) {
    int bid = blockIdx.x;
    if (bid < 586) {
        int g = bid * 256 + threadIdx.x;           // 4-edge group
        if (g < NE / 4) {
            int4 d4 = reinterpret_cast<const int4*>(dst)[g];
            int4 f0 = reinterpret_cast<const int4*>(ef)[g * 3 + 0];
            int4 f1 = reinterpret_cast<const int4*>(ef)[g * 3 + 1];
            int4 f2 = reinterpret_cast<const int4*>(ef)[g * 3 + 2];
            int fa[12] = {f0.x, f0.y, f0.z, f0.w, f1.x, f1.y, f1.z, f1.w,
                          f2.x, f2.y, f2.z, f2.w};
            int dd[4] = {d4.x, d4.y, d4.z, d4.w};
            #pragma unroll
            for (int i = 0; i < 4; ++i) {
                int combo = fa[i * 3] * 25 + fa[i * 3 + 1] * 5 + fa[i * 3 + 2];
                atomicAdd(counts + dd[i] * CW + (combo >> 3),
                          1u << ((combo & 7) * 4));
            }
        }
    } else {
        int idx = (bid - 586) * 256 + threadIdx.x; // 0..16383
        float w = W[idx];
        unsigned short hi = f2bf(w);
        unsigned short lo = f2bf(w - bf2f(hi));
        wsplit[idx] = hi;
        wsplit[16384 + idx] = lo;
    }
}

// ---------------------------------------------------------------------------
// expand: unpack 125 combo counters -> 15 marginal floats, in place (row-local)
// ---------------------------------------------------------------------------
__global__ __launch_bounds__(256) void expand_kernel(unsigned* __restrict__ counts) {
    int n = blockIdx.x * 256 + threadIdx.x;
    if (n >= NN) return;
    unsigned* row = counts + n * CW;
    unsigned wd[16];
    #pragma unroll
    for (int i = 0; i < 4; ++i) {
        uint4 v = reinterpret_cast<uint4*>(row)[i];
        wd[i * 4] = v.x; wd[i * 4 + 1] = v.y; wd[i * 4 + 2] = v.z; wd[i * 4 + 3] = v.w;
    }
    int mi[15];
    #pragma unroll
    for (int j = 0; j < 15; ++j) mi[j] = 0;
    #pragma unroll
    for (int c = 0; c < 125; ++c) {
        int cnt = (int)((wd[c >> 3] >> ((c & 7) * 4)) & 0xFu);
        mi[c / 25] += cnt;
        mi[5 + (c / 5) % 5] += cnt;
        mi[10 + c % 5] += cnt;
    }
    float* frow = (float*)row;
    float4 o;
    o.x = (float)mi[0];  o.y = (float)mi[1];  o.z = (float)mi[2];  o.w = (float)mi[3];
    reinterpret_cast<float4*>(frow)[0] = o;
    o.x = (float)mi[4];  o.y = (float)mi[5];  o.z = (float)mi[6];  o.w = (float)mi[7];
    reinterpret_cast<float4*>(frow)[1] = o;
    o.x = (float)mi[8];  o.y = (float)mi[9];  o.z = (float)mi[10]; o.w = (float)mi[11];
    reinterpret_cast<float4*>(frow)[2] = o;
    o.x = (float)mi[12]; o.y = (float)mi[13]; o.z = (float)mi[14]; o.w = 0.0f;
    reinterpret_cast<float4*>(frow)[3] = o;
}

// ---------------------------------------------------------------------------
// fused: S = m@E via readlane-broadcast FMA; hS = h*S split bf16 hi/lo -> sA;
//        out = hS @ W^T + b via 3-pass bf16 MFMA (verified layouts, round 2)
// ---------------------------------------------------------------------------
__global__ __launch_bounds__(512) void fused_kernel(
        const float* __restrict__ h,
        const float* __restrict__ cntf,        // marginals, stride CW floats
        const float* __restrict__ emb,
        const unsigned short* __restrict__ wsplit,
        const float* __restrict__ b,
        float* __restrict__ out) {
    __shared__ unsigned short sA[2][TM * LDA];     // 34816 B
    __shared__ unsigned short sW[2][128 * LDA];    // 69632 B
    __shared__ float sEmb[16 * LDE];               // 8448 B

    const int tid  = threadIdx.x;
    const int lane = tid & 63;
    const int w    = tid >> 6;
    const int n0   = blockIdx.x * TM;

    // --- stage W hi/lo ---
    #pragma unroll
    for (int i = 0; i < 8; ++i) {
        int cc = tid + i * 512;                    // 0..4095
        int which = cc >> 11;
        int r  = (cc >> 4) & 127;
        int kc = cc & 15;
        uint4 v = reinterpret_cast<const uint4*>(wsplit)[cc];
        *reinterpret_cast<uint4*>(&sW[which][r * LDA + kc * 8]) = v;
    }
    // --- stage emb: 15 used rows (f*5+v) from global rows (f*8+v) ---
    if (tid < 480) {
        int r  = tid >> 5;                         // 0..14
        int f  = r / 5;
        int v  = r - f * 5;
        int cq = tid & 31;
        float4 e = reinterpret_cast<const float4*>(emb)[(f * 8 + v) * 32 + cq];
        *reinterpret_cast<float4*>(&sEmb[r * LDE + cq * 4]) = e;
    }
    __syncthreads();

    // --- Phase 1: lane = node, wave owns d-range [w*16, w*16+16) ---
    {
        const int node  = n0 + lane;
        const bool valid = node < NN;
        float c16[16];
        if (valid) {
            #pragma unroll
            for (int i = 0; i < 4; ++i) {
                float4 cv = reinterpret_cast<const float4*>(cntf + node * CW)[i];
                c16[i * 4] = cv.x; c16[i * 4 + 1] = cv.y;
                c16[i * 4 + 2] = cv.z; c16[i * 4 + 3] = cv.w;
            }
        } else {
            #pragma unroll
            for (int i = 0; i < 16; ++i) c16[i] = 0.0f;
        }
        const int d0 = w * 16;
        // stage wave's E-slice (15 j x 16 d = 240 floats) into 4 VGPRs/lane:
        // lane l holds slice[4l..4l+4), slice idx = j*16 + (d-d0)
        float4 vef = *reinterpret_cast<const float4*>(
            &sEmb[(lane >> 2) * LDE + d0 + (lane & 3) * 4]);
        float vearr[4] = {vef.x, vef.y, vef.z, vef.w};

        float s[16];
        #pragma unroll
        for (int k = 0; k < 16; ++k) s[k] = 0.0f;
        #pragma unroll
        for (int j = 0; j < 15; ++j) {
            #pragma unroll
            for (int k = 0; k < 16; ++k) {
                const int idx = j * 16 + k;
                float ev = __uint_as_float(__builtin_amdgcn_readlane(
                    __float_as_uint(vearr[idx & 3]), idx >> 2));
                s[k] += ev * c16[j];
            }
        }

        float hs[16];
        if (valid) {
            #pragma unroll
            for (int i = 0; i < 4; ++i) {
                float4 hv = reinterpret_cast<const float4*>(h + node * D + d0)[i];
                hs[i * 4]     = hv.x * s[i * 4];
                hs[i * 4 + 1] = hv.y * s[i * 4 + 1];
                hs[i * 4 + 2] = hv.z * s[i * 4 + 2];
                hs[i * 4 + 3] = hv.w * s[i * 4 + 3];
            }
        } else {
            #pragma unroll
            for (int k = 0; k < 16; ++k) hs[k] = 0.0f;
        }

        unsigned ph[8], pl[8];
        #pragma unroll
        for (int k = 0; k < 8; ++k) {
            unsigned short h0 = f2bf(hs[2 * k]);
            unsigned short h1 = f2bf(hs[2 * k + 1]);
            unsigned short l0 = f2bf(hs[2 * k] - bf2f(h0));
            unsigned short l1 = f2bf(hs[2 * k + 1] - bf2f(h1));
            ph[k] = pack2(h0, h1);
            pl[k] = pack2(l0, l1);
        }
        uint4 u;
        u.x = ph[0]; u.y = ph[1]; u.z = ph[2]; u.w = ph[3];
        *reinterpret_cast<uint4*>(&sA[0][lane * LDA + d0]) = u;
        u.x = ph[4]; u.y = ph[5]; u.z = ph[6]; u.w = ph[7];
        *reinterpret_cast<uint4*>(&sA[0][lane * LDA + d0 + 8]) = u;
        u.x = pl[0]; u.y = pl[1]; u.z = pl[2]; u.w = pl[3];
        *reinterpret_cast<uint4*>(&sA[1][lane * LDA + d0]) = u;
        u.x = pl[4]; u.y = pl[5]; u.z = pl[6]; u.w = pl[7];
        *reinterpret_cast<uint4*>(&sA[1][lane * LDA + d0 + 8]) = u;
    }
    __syncthreads();

    // --- Phase 2: MFMA GEMM (identical to round 2, verified) ---
    const int mt = w >> 1;
    const int jc = w & 1;
    const int lr = lane & 15;
    const int lg = lane >> 4;

    f32x4 acc[4];
    #pragma unroll
    for (int jb = 0; jb < 4; ++jb) {
        float bv = b[jc * 64 + jb * 16 + lr];
        f32x4 t = {bv, bv, bv, bv};
        acc[jb] = t;
    }

    const int arow = mt * 16 + lr;
    const int koff = lg * 8;
    #pragma unroll
    for (int kk = 0; kk < 4; ++kk) {
        const int ke = kk * 32 + koff;
        bf16x8 ahi = *reinterpret_cast<const bf16x8*>(&sA[0][arow * LDA + ke]);
        bf16x8 alo = *reinterpret_cast<const bf16x8*>(&sA[1][arow * LDA + ke]);
        bf16x8 whi[4], wlo[4];
        #pragma unroll
        for (int jb = 0; jb < 4; ++jb) {
            int brow = jc * 64 + jb * 16 + lr;
            whi[jb] = *reinterpret_cast<const bf16x8*>(&sW[0][brow * LDA + ke]);
            wlo[jb] = *reinterpret_cast<const bf16x8*>(&sW[1][brow * LDA + ke]);
        }
        #pragma unroll
        for (int jb = 0; jb < 4; ++jb) {
            acc[jb] = __builtin_amdgcn_mfma_f32_16x16x32_bf16(ahi, whi[jb], acc[jb], 0, 0, 0);
            acc[jb] = __builtin_amdgcn_mfma_f32_16x16x32_bf16(alo, whi[jb], acc[jb], 0, 0, 0);
            acc[jb] = __builtin_amdgcn_mfma_f32_16x16x32_bf16(ahi, wlo[jb], acc[jb], 0, 0, 0);
        }
    }

    #pragma unroll
    for (int jb = 0; jb < 4; ++jb) {
        int col = jc * 64 + jb * 16 + lr;
        #pragma unroll
        for (int r = 0; r < 4; ++r) {
            int node = n0 + mt * 16 + lg * 4 + r;
            if (node < NN) out[node * D + col] = acc[jb][r];
        }
    }
}

extern "C" void kernel_launch(void* const* d_in, const int* in_sizes, int n_in,
                              void* d_out, int out_size, void* d_ws, size_t ws_size,
                              hipStream_t stream) {
    const float* h   = (const float*)d_in[0];
    const int*   ef  = (const int*)d_in[1];
    const int*   dst = (const int*)d_in[2];
    const float* emb = (const float*)d_in[3];
    const float* W   = (const float*)d_in[4];
    const float* b   = (const float*)d_in[5];
    float*       out = (float*)d_out;

    unsigned*       counts = (unsigned*)d_ws;                          // 6.4 MB
    unsigned short* wsplit = (unsigned short*)((char*)d_ws + 6400000); // 64 KB

    hipMemsetAsync(counts, 0, NN * CW * 4, stream);
    hist_kernel<<<586 + 64, 256, 0, stream>>>(ef, dst, counts, W, wsplit);
    expand_kernel<<<(NN + 255) / 256, 256, 0, stream>>>(counts);
    fused_kernel<<<(NN + TM - 1) / TM, 512, 0, stream>>>(h, (const float*)counts, emb, wsplit, b, out);
}

// Round 4
// 66.202 us; speedup vs baseline: 2.9293x; 1.4057x over previous
//
#include <hip/hip_runtime.h>

#define NN 100000
#define NE 600000
#define D 128
#define CW 16          // packed count words per node (125 x 4-bit)

// workspace byte offsets
#define OFF_CNTBF  6400000   // [NN][16] bf16 marginals (3.2 MB)
#define OFF_WSPLIT 9600000   // [2][128][128] bf16 W hi/lo (64 KB)
#define OFF_EFRAG  9665536   // [2][8][64][8] bf16 E^T A-frags (16 KB)

typedef __attribute__((ext_vector_type(8))) short bf16x8;
typedef __attribute__((ext_vector_type(4))) float f32x4;

__device__ __forceinline__ unsigned short f2bf(float x) {
    unsigned u = __float_as_uint(x);
    u += 0x7FFFu + ((u >> 16) & 1u);   // RNE
    return (unsigned short)(u >> 16);
}
__device__ __forceinline__ float bf2f(unsigned short s) {
    return __uint_as_float(((unsigned)s) << 16);
}
__device__ __forceinline__ unsigned pack2(unsigned short a, unsigned short b) {
    return (unsigned)a | ((unsigned)b << 16);
}

// ---------------------------------------------------------------------------
// prep: zero counts + W hi/lo split + E^T MFMA A-fragments (d-permuted)
// ---------------------------------------------------------------------------
__global__ __launch_bounds__(256) void prep_kernel(const float* __restrict__ W,
                                                   const float* __restrict__ emb,
                                                   unsigned char* __restrict__ ws) {
    int bid = blockIdx.x;
    if (bid < 1563) {
        int c = bid * 256 + threadIdx.x;            // int4 index into counts
        if (c < 400000) reinterpret_cast<int4*>(ws)[c] = make_int4(0, 0, 0, 0);
    } else if (bid < 1627) {
        int idx = (bid - 1563) * 256 + threadIdx.x; // 0..16383
        float w = W[idx];
        unsigned short hi = f2bf(w);
        unsigned short lo = f2bf(w - bf2f(hi));
        unsigned short* wsplit = (unsigned short*)(ws + OFF_WSPLIT);
        wsplit[idx] = hi;
        wsplit[16384 + idx] = lo;
    } else {
        int i = (bid - 1627) * 256 + threadIdx.x;   // 0..4095 : [t][lane][e]
        int e = i & 7, l = (i >> 3) & 63, t = (i >> 9) & 7;
        int r = l & 15, lg = l >> 4;
        int j = lg * 8 + e;
        int d = 32 * (t >> 1) + 8 * (r >> 2) + 4 * (t & 1) + (r & 3);
        float v = 0.0f;
        if (j < 15) v = emb[((j / 5) * 8 + (j % 5)) * D + d];
        unsigned short hi = f2bf(v);
        unsigned short lo = f2bf(v - bf2f(hi));
        unsigned short* ef = (unsigned short*)(ws + OFF_EFRAG);
        ef[i] = hi;
        ef[4096 + i] = lo;
    }
}

// ---------------------------------------------------------------------------
// hist: ONE packed atomic per edge (combo = f0*25+f1*5+f2, 4-bit counters)
// ---------------------------------------------------------------------------
__global__ __launch_bounds__(256) void hist_kernel(const int* __restrict__ ef,
                                                   const int* __restrict__ dst,
                                                   unsigned* __restrict__ counts) {
    int g = blockIdx.x * 256 + threadIdx.x;        // 4-edge group
    if (g >= NE / 4) return;
    int4 d4 = reinterpret_cast<const int4*>(dst)[g];
    int4 f0 = reinterpret_cast<const int4*>(ef)[g * 3 + 0];
    int4 f1 = reinterpret_cast<const int4*>(ef)[g * 3 + 1];
    int4 f2 = reinterpret_cast<const int4*>(ef)[g * 3 + 2];
    int fa[12] = {f0.x, f0.y, f0.z, f0.w, f1.x, f1.y, f1.z, f1.w,
                  f2.x, f2.y, f2.z, f2.w};
    int dd[4] = {d4.x, d4.y, d4.z, d4.w};
    #pragma unroll
    for (int i = 0; i < 4; ++i) {
        int combo = fa[i * 3] * 25 + fa[i * 3 + 1] * 5 + fa[i * 3 + 2];
        atomicAdd(counts + dd[i] * CW + (combo >> 3), 1u << ((combo & 7) * 4));
    }
}

// ---------------------------------------------------------------------------
// expand: unpack 125 combo nibbles -> 15 bf16 marginals (+pad), frag order
// ---------------------------------------------------------------------------
__global__ __launch_bounds__(256) void expand_kernel(const unsigned* __restrict__ counts,
                                                     unsigned short* __restrict__ cntbf) {
    int n = blockIdx.x * 256 + threadIdx.x;
    if (n >= NN) return;
    const unsigned* row = counts + n * CW;
    unsigned wd[16];
    #pragma unroll
    for (int i = 0; i < 4; ++i) {
        uint4 v = reinterpret_cast<const uint4*>(row)[i];
        wd[i * 4] = v.x; wd[i * 4 + 1] = v.y; wd[i * 4 + 2] = v.z; wd[i * 4 + 3] = v.w;
    }
    int mi[15];
    #pragma unroll
    for (int j = 0; j < 15; ++j) mi[j] = 0;
    #pragma unroll
    for (int c = 0; c < 125; ++c) {
        int cnt = (int)((wd[c >> 3] >> ((c & 7) * 4)) & 0xFu);
        mi[c / 25] += cnt;
        mi[5 + (c / 5) % 5] += cnt;
        mi[10 + c % 5] += cnt;
    }
    unsigned short o[16];
    #pragma unroll
    for (int j = 0; j < 15; ++j) o[j] = f2bf((float)mi[j]);  // exact (<256)
    o[15] = 0;
    uint4 u;
    u.x = pack2(o[0], o[1]);   u.y = pack2(o[2], o[3]);
    u.z = pack2(o[4], o[5]);   u.w = pack2(o[6], o[7]);
    reinterpret_cast<uint4*>(cntbf + n * 16)[0] = u;
    u.x = pack2(o[8], o[9]);   u.y = pack2(o[10], o[11]);
    u.z = pack2(o[12], o[13]); u.w = pack2(o[14], o[15]);
    reinterpret_cast<uint4*>(cntbf + n * 16)[1] = u;
}

// ---------------------------------------------------------------------------
// fused: phase1  S^T = E^T @ cnt^T via 8 MFMA (E hi/lo 2-pass), hs = h*S,
//                single-bf16 pack -> sA (XOR-swizzled, A-frag layout)
//        phase2  out = a@Whi + a@Wlo + b  (W exact via hi/lo, 32 MFMA/wave)
// LDS 80 KB exactly -> 2 blocks/CU (16 waves).
// ---------------------------------------------------------------------------
__global__ __launch_bounds__(512, 4) void fused_kernel(
        const float* __restrict__ h,
        const unsigned short* __restrict__ cntbf,
        const unsigned short* __restrict__ efrag,
        const unsigned short* __restrict__ wsplit,
        const float* __restrict__ b,
        float* __restrict__ out) {
    __shared__ unsigned short sW[2][128 * 128];    // 65536 B, swizzled
    __shared__ unsigned short sA[64 * 128];        // 16384 B, swizzled

    const int tid  = threadIdx.x;
    const int lane = tid & 63;
    const int w    = tid >> 6;
    const int n0   = blockIdx.x * 64;
    const int lr   = lane & 15;
    const int lg   = lane >> 4;

    char* sWb = (char*)&sW[0][0];
    char* sAb = (char*)&sA[0];

    // --- stage W hi/lo, swizzled: byte ^= (row&7)<<4 ---
    #pragma unroll
    for (int i = 0; i < 8; ++i) {
        int c  = tid + i * 512;                    // 0..4095 16B-chunks
        int p  = c >> 11;
        int r  = (c >> 4) & 127;
        int kc = c & 15;
        int byte = p * 32768 + r * 256 + ((kc * 16) ^ ((r & 7) << 4));
        *reinterpret_cast<uint4*>(sWb + byte) = reinterpret_cast<const uint4*>(wsplit)[c];
    }

    // --- phase 1: wave (ng = w&3 node-group, th = w>>2 d-half) ---
    const int ng   = w & 3;
    const int th   = w >> 2;
    const int node = n0 + ng * 16 + lr;
    const bool valid = node < NN;

    bf16x8 cfrag = {0, 0, 0, 0, 0, 0, 0, 0};
    if (valid && lg < 2)
        cfrag = *reinterpret_cast<const bf16x8*>(cntbf + node * 16 + lg * 8);

    f32x4 s[4];
    #pragma unroll
    for (int ti = 0; ti < 4; ++ti) { f32x4 z = {0, 0, 0, 0}; s[ti] = z; }
    #pragma unroll
    for (int p = 0; p < 2; ++p) {
        #pragma unroll
        for (int ti = 0; ti < 4; ++ti) {
            int t = th * 4 + ti;
            bf16x8 ef = *reinterpret_cast<const bf16x8*>(efrag + p * 4096 + t * 512 + lane * 8);
            s[ti] = __builtin_amdgcn_mfma_f32_16x16x32_bf16(ef, cfrag, s[ti], 0, 0, 0);
        }
    }

    #pragma unroll
    for (int q = 0; q < 2; ++q) {
        const int u = th * 2 + q;
        float hv[8];
        if (valid) {
            float4 h0 = *reinterpret_cast<const float4*>(h + node * D + u * 32 + lg * 8);
            float4 h1 = *reinterpret_cast<const float4*>(h + node * D + u * 32 + lg * 8 + 4);
            hv[0] = h0.x; hv[1] = h0.y; hv[2] = h0.z; hv[3] = h0.w;
            hv[4] = h1.x; hv[5] = h1.y; hv[6] = h1.z; hv[7] = h1.w;
        } else {
            #pragma unroll
            for (int e = 0; e < 8; ++e) hv[e] = 0.0f;
        }
        unsigned short o[8];
        #pragma unroll
        for (int e = 0; e < 8; ++e)
            o[e] = f2bf(hv[e] * s[q * 2 + (e >> 2)][e & 3]);
        uint4 uo;
        uo.x = pack2(o[0], o[1]); uo.y = pack2(o[2], o[3]);
        uo.z = pack2(o[4], o[5]); uo.w = pack2(o[6], o[7]);
        int row  = ng * 16 + lr;
        int byte = row * 256 + ((u * 64 + lg * 16) ^ ((row & 7) << 4));
        *reinterpret_cast<uint4*>(sAb + byte) = uo;
    }
    __syncthreads();

    // --- phase 2: wave (mt = w>>1, jc = w&1), 2-pass W hi/lo ---
    const int mt = w >> 1;
    const int jc = w & 1;

    f32x4 acc[4];
    #pragma unroll
    for (int jb = 0; jb < 4; ++jb) {
        float bv = b[jc * 64 + jb * 16 + lr];
        f32x4 t = {bv, bv, bv, bv};
        acc[jb] = t;
    }

    const int arow = mt * 16 + lr;
    #pragma unroll
    for (int kk = 0; kk < 4; ++kk) {
        int abyte = arow * 256 + ((kk * 64 + lg * 16) ^ ((arow & 7) << 4));
        bf16x8 av = *reinterpret_cast<const bf16x8*>(sAb + abyte);
        #pragma unroll
        for (int jb = 0; jb < 4; ++jb) {
            int brow  = jc * 64 + jb * 16 + lr;
            int wbyte = brow * 256 + ((kk * 64 + lg * 16) ^ ((brow & 7) << 4));
            bf16x8 whi = *reinterpret_cast<const bf16x8*>(sWb + wbyte);
            bf16x8 wlo = *reinterpret_cast<const bf16x8*>(sWb + 32768 + wbyte);
            acc[jb] = __builtin_amdgcn_mfma_f32_16x16x32_bf16(av, whi, acc[jb], 0, 0, 0);
            acc[jb] = __builtin_amdgcn_mfma_f32_16x16x32_bf16(av, wlo, acc[jb], 0, 0, 0);
        }
    }

    #pragma unroll
    for (int jb = 0; jb < 4; ++jb) {
        int col = jc * 64 + jb * 16 + lr;
        #pragma unroll
        for (int r = 0; r < 4; ++r) {
            int n2 = n0 + mt * 16 + lg * 4 + r;
            if (n2 < NN) out[n2 * D + col] = acc[jb][r];
        }
    }
}

extern "C" void kernel_launch(void* const* d_in, const int* in_sizes, int n_in,
                              void* d_out, int out_size, void* d_ws, size_t ws_size,
                              hipStream_t stream) {
    const float* h   = (const float*)d_in[0];
    const int*   ef  = (const int*)d_in[1];
    const int*   dst = (const int*)d_in[2];
    const float* emb = (const float*)d_in[3];
    const float* W   = (const float*)d_in[4];
    const float* b   = (const float*)d_in[5];
    float*       out = (float*)d_out;

    unsigned char*  ws     = (unsigned char*)d_ws;
    unsigned*       counts = (unsigned*)ws;                         // 6.4 MB
    unsigned short* cntbf  = (unsigned short*)(ws + OFF_CNTBF);     // 3.2 MB
    unsigned short* wsplit = (unsigned short*)(ws + OFF_WSPLIT);    // 64 KB
    unsigned short* efr    = (unsigned short*)(ws + OFF_EFRAG);     // 16 KB

    prep_kernel<<<1563 + 64 + 16, 256, 0, stream>>>(W, emb, ws);
    hist_kernel<<<(NE / 4 + 255) / 256, 256, 0, stream>>>(ef, dst, counts);
    expand_kernel<<<(NN + 255) / 256, 256, 0, stream>>>(counts, cntbf);
    fused_kernel<<<(NN + 63) / 64, 512, 0, stream>>>(h, cntbf, efr, wsplit, b, out);
}

// Round 5
// 63.527 us; speedup vs baseline: 3.0527x; 1.0421x over previous
//
#include <hip/hip_runtime.h>

#define NN 100000
#define NE 600000
#define D 128
#define CW 16          // packed count words per node (125 x 4-bit)

// workspace byte offsets
#define OFF_CNTBF  6400000   // [NN][16] bf16 marginals (3.2 MB)
#define OFF_WSPLIT 9600000   // [2][128][128] bf16 W hi/lo (64 KB)
#define OFF_EFRAG  9665536   // [2][8][64][8] bf16 E^T A-frags (16 KB)

typedef __attribute__((ext_vector_type(8))) short bf16x8;
typedef __attribute__((ext_vector_type(4))) float f32x4;

__device__ __forceinline__ unsigned short f2bf(float x) {
    unsigned u = __float_as_uint(x);
    u += 0x7FFFu + ((u >> 16) & 1u);   // RNE
    return (unsigned short)(u >> 16);
}
__device__ __forceinline__ float bf2f(unsigned short s) {
    return __uint_as_float(((unsigned)s) << 16);
}
__device__ __forceinline__ unsigned pack2(unsigned short a, unsigned short b) {
    return (unsigned)a | ((unsigned)b << 16);
}

// ---------------------------------------------------------------------------
// prep: zero counts + W hi/lo split + E^T MFMA A-fragments (d-permuted)
// ---------------------------------------------------------------------------
__global__ __launch_bounds__(256) void prep_kernel(const float* __restrict__ W,
                                                   const float* __restrict__ emb,
                                                   unsigned char* __restrict__ ws) {
    int bid = blockIdx.x;
    if (bid < 1563) {
        int c = bid * 256 + threadIdx.x;            // int4 index into counts
        if (c < 400000) reinterpret_cast<int4*>(ws)[c] = make_int4(0, 0, 0, 0);
    } else if (bid < 1627) {
        int idx = (bid - 1563) * 256 + threadIdx.x; // 0..16383
        float w = W[idx];
        unsigned short hi = f2bf(w);
        unsigned short lo = f2bf(w - bf2f(hi));
        unsigned short* wsplit = (unsigned short*)(ws + OFF_WSPLIT);
        wsplit[idx] = hi;
        wsplit[16384 + idx] = lo;
    } else {
        int i = (bid - 1627) * 256 + threadIdx.x;   // 0..4095 : [t][lane][e]
        int e = i & 7, l = (i >> 3) & 63, t = (i >> 9) & 7;
        int r = l & 15, lg = l >> 4;
        int j = lg * 8 + e;
        int d = 32 * (t >> 1) + 8 * (r >> 2) + 4 * (t & 1) + (r & 3);
        float v = 0.0f;
        if (j < 15) v = emb[((j / 5) * 8 + (j % 5)) * D + d];
        unsigned short hi = f2bf(v);
        unsigned short lo = f2bf(v - bf2f(hi));
        unsigned short* ef = (unsigned short*)(ws + OFF_EFRAG);
        ef[i] = hi;
        ef[4096 + i] = lo;
    }
}

// ---------------------------------------------------------------------------
// hist: ONE packed atomic per edge (combo = f0*25+f1*5+f2, 4-bit counters)
// ---------------------------------------------------------------------------
__global__ __launch_bounds__(256) void hist_kernel(const int* __restrict__ ef,
                                                   const int* __restrict__ dst,
                                                   unsigned* __restrict__ counts) {
    int g = blockIdx.x * 256 + threadIdx.x;        // 4-edge group
    if (g >= NE / 4) return;
    int4 d4 = reinterpret_cast<const int4*>(dst)[g];
    int4 f0 = reinterpret_cast<const int4*>(ef)[g * 3 + 0];
    int4 f1 = reinterpret_cast<const int4*>(ef)[g * 3 + 1];
    int4 f2 = reinterpret_cast<const int4*>(ef)[g * 3 + 2];
    int fa[12] = {f0.x, f0.y, f0.z, f0.w, f1.x, f1.y, f1.z, f1.w,
                  f2.x, f2.y, f2.z, f2.w};
    int dd[4] = {d4.x, d4.y, d4.z, d4.w};
    #pragma unroll
    for (int i = 0; i < 4; ++i) {
        int combo = fa[i * 3] * 25 + fa[i * 3 + 1] * 5 + fa[i * 3 + 2];
        atomicAdd(counts + dd[i] * CW + (combo >> 3), 1u << ((combo & 7) * 4));
    }
}

// ---------------------------------------------------------------------------
// expand: unpack 125 combo nibbles -> 15 bf16 marginals (+pad), frag order
// ---------------------------------------------------------------------------
__global__ __launch_bounds__(256) void expand_kernel(const unsigned* __restrict__ counts,
                                                     unsigned short* __restrict__ cntbf) {
    int n = blockIdx.x * 256 + threadIdx.x;
    if (n >= NN) return;
    const unsigned* row = counts + n * CW;
    unsigned wd[16];
    #pragma unroll
    for (int i = 0; i < 4; ++i) {
        uint4 v = reinterpret_cast<const uint4*>(row)[i];
        wd[i * 4] = v.x; wd[i * 4 + 1] = v.y; wd[i * 4 + 2] = v.z; wd[i * 4 + 3] = v.w;
    }
    int mi[15];
    #pragma unroll
    for (int j = 0; j < 15; ++j) mi[j] = 0;
    #pragma unroll
    for (int c = 0; c < 125; ++c) {
        int cnt = (int)((wd[c >> 3] >> ((c & 7) * 4)) & 0xFu);
        mi[c / 25] += cnt;
        mi[5 + (c / 5) % 5] += cnt;
        mi[10 + c % 5] += cnt;
    }
    unsigned short o[16];
    #pragma unroll
    for (int j = 0; j < 15; ++j) o[j] = f2bf((float)mi[j]);  // exact (<256)
    o[15] = 0;
    uint4 u;
    u.x = pack2(o[0], o[1]);   u.y = pack2(o[2], o[3]);
    u.z = pack2(o[4], o[5]);   u.w = pack2(o[6], o[7]);
    reinterpret_cast<uint4*>(cntbf + n * 16)[0] = u;
    u.x = pack2(o[8], o[9]);   u.y = pack2(o[10], o[11]);
    u.z = pack2(o[12], o[13]); u.w = pack2(o[14], o[15]);
    reinterpret_cast<uint4*>(cntbf + n * 16)[1] = u;
}

// ---------------------------------------------------------------------------
// fused v5: per-wave end-to-end, NO sA round-trip.
//   phase1: S^T = E^T @ cnt^T (16 MFMA, all 8 d-chunks, this wave's 16 nodes)
//           -> afrag[kk] = bf16(h * S) entirely in registers (layout matches
//              phase-2 A-fragment by construction of the efrag d-permutation)
//   phase2: out = afrag@Whi + afrag@Wlo + b   (64 MFMA, W from swizzled LDS)
// Block 512 = 8 waves x 16 nodes = 128 nodes; LDS 64 KB -> 2 blocks/CU.
// Single barrier (after W stage).
// ---------------------------------------------------------------------------
__global__ __launch_bounds__(512, 4) void fused_kernel(
        const float* __restrict__ h,
        const unsigned short* __restrict__ cntbf,
        const unsigned short* __restrict__ efrag,
        const unsigned short* __restrict__ wsplit,
        const float* __restrict__ b,
        float* __restrict__ out) {
    __shared__ unsigned short sW[2][128 * 128];    // 65536 B, swizzled

    const int tid  = threadIdx.x;
    const int lane = tid & 63;
    const int w    = tid >> 6;
    const int n0   = blockIdx.x * 128;
    const int lr   = lane & 15;
    const int lg   = lane >> 4;

    char* sWb = (char*)&sW[0][0];

    // --- stage W hi/lo, swizzled: byte ^= (row&7)<<4 ---
    #pragma unroll
    for (int i = 0; i < 8; ++i) {
        int c  = tid + i * 512;                    // 0..4095 16B-chunks
        int p  = c >> 11;
        int r  = (c >> 4) & 127;
        int kc = c & 15;
        int byte = p * 32768 + r * 256 + ((kc * 16) ^ ((r & 7) << 4));
        *reinterpret_cast<uint4*>(sWb + byte) = reinterpret_cast<const uint4*>(wsplit)[c];
    }

    // --- phase 1: this wave's 16 nodes, all d ---
    const int node  = n0 + w * 16 + lr;
    const bool valid = node < NN;

    // h gather issued first (L3 latency hides under efrag/MFMA chain)
    float hv[4][8];
    #pragma unroll
    for (int kk = 0; kk < 4; ++kk) {
        if (valid) {
            float4 h0 = *reinterpret_cast<const float4*>(h + node * D + kk * 32 + lg * 8);
            float4 h1 = *reinterpret_cast<const float4*>(h + node * D + kk * 32 + lg * 8 + 4);
            hv[kk][0] = h0.x; hv[kk][1] = h0.y; hv[kk][2] = h0.z; hv[kk][3] = h0.w;
            hv[kk][4] = h1.x; hv[kk][5] = h1.y; hv[kk][6] = h1.z; hv[kk][7] = h1.w;
        } else {
            #pragma unroll
            for (int e = 0; e < 8; ++e) hv[kk][e] = 0.0f;
        }
    }

    bf16x8 cfrag = {0, 0, 0, 0, 0, 0, 0, 0};
    if (valid && lg < 2)
        cfrag = *reinterpret_cast<const bf16x8*>(cntbf + node * 16 + lg * 8);

    f32x4 s[8];
    #pragma unroll
    for (int t = 0; t < 8; ++t) { f32x4 z = {0, 0, 0, 0}; s[t] = z; }
    #pragma unroll
    for (int p = 0; p < 2; ++p) {
        #pragma unroll
        for (int t = 0; t < 8; ++t) {
            bf16x8 ef = *reinterpret_cast<const bf16x8*>(efrag + p * 4096 + t * 512 + lane * 8);
            s[t] = __builtin_amdgcn_mfma_f32_16x16x32_bf16(ef, cfrag, s[t], 0, 0, 0);
        }
    }

    // pack A-fragments in-register (d(t,row) permutation makes this direct)
    bf16x8 afrag[4];
    #pragma unroll
    for (int kk = 0; kk < 4; ++kk) {
        unsigned short o[8];
        #pragma unroll
        for (int e = 0; e < 8; ++e)
            o[e] = f2bf(hv[kk][e] * s[kk * 2 + (e >> 2)][e & 3]);
        unsigned uo[4];
        uo[0] = pack2(o[0], o[1]); uo[1] = pack2(o[2], o[3]);
        uo[2] = pack2(o[4], o[5]); uo[3] = pack2(o[6], o[7]);
        afrag[kk] = *reinterpret_cast<bf16x8*>(uo);
    }
    __syncthreads();

    // --- phase 2: 16 nodes x 128 cols, W hi/lo 2-pass from LDS ---
    f32x4 acc[8];
    #pragma unroll
    for (int jb = 0; jb < 8; ++jb) {
        float bv = b[jb * 16 + lr];
        f32x4 t = {bv, bv, bv, bv};
        acc[jb] = t;
    }

    #pragma unroll
    for (int kk = 0; kk < 4; ++kk) {
        #pragma unroll
        for (int jb = 0; jb < 8; ++jb) {
            int brow  = jb * 16 + lr;
            int wbyte = brow * 256 + ((kk * 64 + lg * 16) ^ ((brow & 7) << 4));
            bf16x8 whi = *reinterpret_cast<const bf16x8*>(sWb + wbyte);
            bf16x8 wlo = *reinterpret_cast<const bf16x8*>(sWb + 32768 + wbyte);
            acc[jb] = __builtin_amdgcn_mfma_f32_16x16x32_bf16(afrag[kk], whi, acc[jb], 0, 0, 0);
            acc[jb] = __builtin_amdgcn_mfma_f32_16x16x32_bf16(afrag[kk], wlo, acc[jb], 0, 0, 0);
        }
    }

    #pragma unroll
    for (int jb = 0; jb < 8; ++jb) {
        int col = jb * 16 + lr;
        #pragma unroll
        for (int r = 0; r < 4; ++r) {
            int n2 = n0 + w * 16 + lg * 4 + r;
            if (n2 < NN) out[n2 * D + col] = acc[jb][r];
        }
    }
}

extern "C" void kernel_launch(void* const* d_in, const int* in_sizes, int n_in,
                              void* d_out, int out_size, void* d_ws, size_t ws_size,
                              hipStream_t stream) {
    const float* h   = (const float*)d_in[0];
    const int*   ef  = (const int*)d_in[1];
    const int*   dst = (const int*)d_in[2];
    const float* emb = (const float*)d_in[3];
    const float* W   = (const float*)d_in[4];
    const float* b   = (const float*)d_in[5];
    float*       out = (float*)d_out;

    unsigned char*  ws     = (unsigned char*)d_ws;
    unsigned*       counts = (unsigned*)ws;                         // 6.4 MB
    unsigned short* cntbf  = (unsigned short*)(ws + OFF_CNTBF);     // 3.2 MB
    unsigned short* wsplit = (unsigned short*)(ws + OFF_WSPLIT);    // 64 KB
    unsigned short* efr    = (unsigned short*)(ws + OFF_EFRAG);     // 16 KB

    prep_kernel<<<1563 + 64 + 16, 256, 0, stream>>>(W, emb, ws);
    hist_kernel<<<(NE / 4 + 255) / 256, 256, 0, stream>>>(ef, dst, counts);
    expand_kernel<<<(NN + 255) / 256, 256, 0, stream>>>(counts, cntbf);
    fused_kernel<<<(NN + 127) / 128, 512, 0, stream>>>(h, cntbf, efr, wsplit, b, out);
}